// Round 2
// baseline (737.856 us; speedup 1.0000x reference)
//
#include <hip/hip_runtime.h>
#include <hip/hip_bf16.h>
#include <math.h>

typedef __hip_bfloat16 bf16;

#define NB 2
#define HH 96
#define WW 96
#define CC 256
#define NHEADS 8
#define PP 25
#define DHH 32
#define HIDN 1024
#define LQ (HH*WW)          // 9216
#define TT (NB*LQ)          // 18432

__device__ __forceinline__ float b2f(bf16 v){ return __bfloat162float(v); }
__device__ __forceinline__ bf16  f2b(float v){ return __float2bfloat16(v); }
__device__ __forceinline__ float bits2f(unsigned short u){ return __uint_as_float(((unsigned)u) << 16); }

// ---------------- LayerNorm (one token per block, 256 threads = 256 channels) ----
// input fp32, output bf16
__global__ __launch_bounds__(256) void ln_kernel(const float* __restrict__ x,
                                                 const float* __restrict__ g,
                                                 const float* __restrict__ b,
                                                 bf16* __restrict__ out)
{
    const int t = blockIdx.x;
    const int c = threadIdx.x;
    float v = x[(size_t)t*CC + c];
    __shared__ float s1[256];
    __shared__ float s2[256];
    s1[c] = v; s2[c] = v*v;
    __syncthreads();
    #pragma unroll
    for (int s = 128; s > 0; s >>= 1) {
        if (c < s) { s1[c] += s1[c+s]; s2[c] += s2[c+s]; }
        __syncthreads();
    }
    float mean = s1[0] * (1.f/CC);
    float var  = s2[0] * (1.f/CC) - mean*mean;
    float rs   = 1.f / sqrtf(var + 1e-5f);
    out[(size_t)t*CC + c] = f2b((v - mean) * rs * g[c] + b[c]);
}

// ---------------- GEMM: A[M,K] bf16 @ W[K,N] fp32 + bias fp32, fp32 accumulate ---
// EPI: 0 = store bf16; 1 = store fp32; 2 = gelu->bf16; 3 = +resid(fp32)->fp32
template<int EPI>
__global__ __launch_bounds__(256) void gemm_kernel(const bf16* __restrict__ A,
                                                   const float* __restrict__ W,
                                                   const float* __restrict__ bias,
                                                   void* __restrict__ outv,
                                                   const float* __restrict__ resid,
                                                   int K, int Nc)
{
    __shared__ float As[32][68];
    __shared__ float Bs[32][68];
    const int tid = threadIdx.x;
    const int bm = blockIdx.x, bn = blockIdx.y;
    const int tx = tid & 15, ty = tid >> 4;
    const int arow = tid >> 2, acol = (tid & 3) << 3;   // A: 64 rows x 32 k, 8 k's each
    const int brow = tid >> 3, bcol = (tid & 7) << 3;   // W: 32 k   x 64 n, 8 n's each
    const int colbase = bn * 64;
    float acc[4][4] = {};

    for (int k0 = 0; k0 < K; k0 += 32) {
        // A tile (bf16 internal buffer; always in bounds: M%64==0, K%32==0)
        const bf16* ap = A + (size_t)(bm*64 + arow)*K + (k0 + acol);
        uint4 av = *reinterpret_cast<const uint4*>(ap);
        const unsigned short* as = reinterpret_cast<const unsigned short*>(&av);
        #pragma unroll
        for (int i = 0; i < 8; i++) As[acol + i][arow] = bits2f(as[i]);

        // W tile fp32 (guard N tail)
        const int wrow = k0 + brow;
        const int wcol = colbase + bcol;
        const float* wp = W + (size_t)wrow*Nc + wcol;
        if (wcol + 7 < Nc) {
            float4 w0 = *reinterpret_cast<const float4*>(wp);
            float4 w1 = *reinterpret_cast<const float4*>(wp + 4);
            Bs[brow][bcol+0]=w0.x; Bs[brow][bcol+1]=w0.y;
            Bs[brow][bcol+2]=w0.z; Bs[brow][bcol+3]=w0.w;
            Bs[brow][bcol+4]=w1.x; Bs[brow][bcol+5]=w1.y;
            Bs[brow][bcol+6]=w1.z; Bs[brow][bcol+7]=w1.w;
        } else {
            #pragma unroll
            for (int i = 0; i < 8; i++) {
                int cc2 = wcol + i;
                Bs[brow][bcol + i] = (cc2 < Nc) ? wp[i] : 0.f;
            }
        }
        __syncthreads();

        #pragma unroll
        for (int k = 0; k < 32; k++) {
            float4 a4 = *reinterpret_cast<const float4*>(&As[k][ty << 2]);
            float4 b4 = *reinterpret_cast<const float4*>(&Bs[k][tx << 2]);
            float av4[4] = {a4.x, a4.y, a4.z, a4.w};
            float bv4[4] = {b4.x, b4.y, b4.z, b4.w};
            #pragma unroll
            for (int i = 0; i < 4; i++)
                #pragma unroll
                for (int j = 0; j < 4; j++)
                    acc[i][j] += av4[i] * bv4[j];
        }
        __syncthreads();
    }

    #pragma unroll
    for (int i = 0; i < 4; i++) {
        const int row = bm*64 + (ty << 2) + i;
        #pragma unroll
        for (int j = 0; j < 4; j++) {
            const int col = colbase + (tx << 2) + j;
            if (col >= Nc) continue;
            float v = acc[i][j] + bias[col];
            size_t o = (size_t)row * Nc + col;
            if (EPI == 0) {
                ((bf16*)outv)[o] = f2b(v);
            } else if (EPI == 1) {
                ((float*)outv)[o] = v;
            } else if (EPI == 2) {
                ((bf16*)outv)[o] = f2b(0.5f * v * (1.f + erff(v * 0.70710678118654752f)));
            } else { // 3: add fp32 residual, store fp32
                ((float*)outv)[o] = v + resid[o];
            }
        }
    }
}

// ---------------- Softmax over P=25 per (token, head), in place ------------------
__global__ __launch_bounds__(256) void softmax_kernel(float* __restrict__ aw)
{
    const int gid = blockIdx.x * 256 + threadIdx.x;
    if (gid >= TT * NHEADS) return;
    float* p = aw + (size_t)(gid >> 3) * (NHEADS*PP) + (gid & 7) * PP;
    float m = p[0];
    #pragma unroll
    for (int i = 1; i < PP; i++) m = fmaxf(m, p[i]);
    float e[PP], s = 0.f;
    #pragma unroll
    for (int i = 0; i < PP; i++) { e[i] = expf(p[i] - m); s += e[i]; }
    float inv = 1.f / s;
    #pragma unroll
    for (int i = 0; i < PP; i++) p[i] = e[i] * inv;
}

// ---------------- Deformable bilinear sampling + attention-weighted sum ----------
// One 32-lane group per (token, head); lane = dh channel.
__global__ __launch_bounds__(256) void sample_kernel(const bf16* __restrict__ val,
                                                     const float* __restrict__ off,
                                                     const float* __restrict__ aw,
                                                     const float* __restrict__ refp,
                                                     bf16* __restrict__ samp)
{
    const int group = threadIdx.x >> 5;
    const int lane  = threadIdx.x & 31;
    const int pair  = blockIdx.x * 8 + group;    // [0, TT*NHEADS)
    const int t = pair >> 3;
    const int h = pair & 7;
    const int n = t / LQ;

    const float rx = refp[(size_t)t*2 + 0];
    const float ry = refp[(size_t)t*2 + 1];
    const float* offp = off + (size_t)t*(NHEADS*PP*2) + h*(PP*2);
    const float* awp  = aw  + (size_t)t*(NHEADS*PP)   + h*PP;
    const bf16* vbase = val + (size_t)n*LQ*CC + h*DHH + lane;

    float acc = 0.f;
    for (int p = 0; p < PP; p++) {
        const float a  = awp[p];
        const float gx = (rx + offp[2*p + 0] * (1.f/96.f)) * 96.f - 0.5f;
        const float gy = (ry + offp[2*p + 1] * (1.f/96.f)) * 96.f - 0.5f;
        const float x0 = floorf(gx), y0 = floorf(gy);
        const float fx = gx - x0, fy = gy - y0;
        const int ix = (int)x0, iy = (int)y0;
        #pragma unroll
        for (int d = 0; d < 4; d++) {
            const int dx = d & 1, dy = d >> 1;
            const int xi = ix + dx, yi = iy + dy;
            const float wgt = (dx ? fx : 1.f - fx) * (dy ? fy : 1.f - fy);
            const bool valid = (xi >= 0) & (xi <= WW-1) & (yi >= 0) & (yi <= HH-1);
            const int xc = min(max(xi, 0), WW-1);
            const int yc = min(max(yi, 0), HH-1);
            const int idx = yc * WW + xc;
            const float v = b2f(vbase[(size_t)idx * CC]);
            acc += a * wgt * (valid ? 1.f : 0.f) * v;
        }
    }
    samp[(size_t)t*CC + h*DHH + lane] = f2b(acc);
}

// ---------------- Launch ---------------------------------------------------------
extern "C" void kernel_launch(void* const* d_in, const int* in_sizes, int n_in,
                              void* d_out, int out_size, void* d_ws, size_t ws_size,
                              hipStream_t stream)
{
    const float* x      = (const float*)d_in[0];
    const float* refp   = (const float*)d_in[1];
    const float* ln1_g  = (const float*)d_in[4];
    const float* ln1_b  = (const float*)d_in[5];
    const float* w_off  = (const float*)d_in[6];
    const float* b_off  = (const float*)d_in[7];
    const float* w_attn = (const float*)d_in[8];
    const float* b_attn = (const float*)d_in[9];
    const float* w_val  = (const float*)d_in[10];
    const float* b_val  = (const float*)d_in[11];
    const float* w_out  = (const float*)d_in[12];
    const float* b_out  = (const float*)d_in[13];
    const float* ln2_g  = (const float*)d_in[14];
    const float* ln2_b  = (const float*)d_in[15];
    const float* w_fc1  = (const float*)d_in[16];
    const float* b_fc1  = (const float*)d_in[17];
    const float* w_fc2  = (const float*)d_in[18];
    const float* b_fc2  = (const float*)d_in[19];

    // workspace layout (all 16B aligned)
    char* wsb = (char*)d_ws;
    bf16*  q    = (bf16*) (wsb + 0);          //  9,437,184  (TT*256 bf16)
    bf16*  val  = (bf16*) (wsb + 9437184);    //  9,437,184
    float* offb = (float*)(wsb + 18874368);   // 29,491,200  (TT*400 f32)
    float* awb  = (float*)(wsb + 48365568);   // 14,745,600  (TT*200 f32)
    bf16*  samp = (bf16*) (wsb + 63111168);   //  9,437,184
    float* x1   = (float*)(wsb + 72548352);   // 18,874,368  -> total 91,422,720
    bf16*  hid  = (bf16*) (wsb + 0);          // reuse q/val/off region (37.7MB < 63.1MB)
    bf16*  y0   = samp;                       // reuse samp after out-GEMM consumed it

    if (ws_size < 91422720) return;  // fail visibly rather than corrupt

    const dim3 blk(256);
    // 1. LN1
    ln_kernel<<<TT, blk, 0, stream>>>(x, ln1_g, ln1_b, q);
    // 2. value / offsets / attn-logits GEMMs
    gemm_kernel<0><<<dim3(TT/64, 4),  blk, 0, stream>>>(q, w_val,  b_val,  (void*)val,  nullptr, CC, CC);
    gemm_kernel<1><<<dim3(TT/64, 7),  blk, 0, stream>>>(q, w_off,  b_off,  (void*)offb, nullptr, CC, NHEADS*PP*2);
    gemm_kernel<1><<<dim3(TT/64, 4),  blk, 0, stream>>>(q, w_attn, b_attn, (void*)awb,  nullptr, CC, NHEADS*PP);
    // 3. softmax over P
    softmax_kernel<<<dim3((TT*NHEADS + 255)/256), blk, 0, stream>>>(awb);
    // 4. deformable sampling (one 32-lane group per (t,h))
    sample_kernel<<<dim3(TT), blk, 0, stream>>>(val, offb, awb, refp, samp);
    // 5. out-projection + residual -> x1 (fp32)
    gemm_kernel<3><<<dim3(TT/64, 4),  blk, 0, stream>>>(samp, w_out, b_out, (void*)x1, x, CC, CC);
    // 6. LN2
    ln_kernel<<<TT, blk, 0, stream>>>(x1, ln2_g, ln2_b, y0);
    // 7. fc1 + gelu
    gemm_kernel<2><<<dim3(TT/64, 16), blk, 0, stream>>>(y0, w_fc1, b_fc1, (void*)hid, nullptr, CC, HIDN);
    // 8. fc2 + residual -> out (fp32)
    gemm_kernel<3><<<dim3(TT/64, 4),  blk, 0, stream>>>(hid, w_fc2, b_fc2, d_out, x1, HIDN, CC);
}

// Round 3
// 296.430 us; speedup vs baseline: 2.4891x; 2.4891x over previous
//
#include <hip/hip_runtime.h>
#include <hip/hip_bf16.h>
#include <math.h>

typedef __hip_bfloat16 bf16;
typedef __attribute__((ext_vector_type(8))) short short8;
typedef __attribute__((ext_vector_type(4))) float f32x4;

#define NB 2
#define HH 96
#define WW 96
#define CC 256
#define NHEADS 8
#define PP 25
#define DHH 32
#define HIDN 1024
#define LQ (HH*WW)          // 9216
#define TT (NB*LQ)          // 18432
#define NCAT 640            // 400 off + 200 attn + 40 pad

__device__ __forceinline__ float b2f(bf16 v){ return __bfloat162float(v); }
__device__ __forceinline__ bf16  f2b(float v){ return __float2bfloat16(v); }
__device__ __forceinline__ float lo_bf(unsigned u){ return __uint_as_float(u << 16); }
__device__ __forceinline__ float hi_bf(unsigned u){ return __uint_as_float(u & 0xffff0000u); }

__device__ __forceinline__ void gl2lds16(const void* g, void* l) {
    __builtin_amdgcn_global_load_lds(
        (const __attribute__((address_space(1))) unsigned int*)g,
        (__attribute__((address_space(3))) unsigned int*)l, 16, 0, 0);
}

// ---------------- weight prep: transpose fp32 [K][N] -> bf16 [N][K] -------------
__global__ __launch_bounds__(256) void prep_t(const float* __restrict__ src,
                                              bf16* __restrict__ dst,
                                              int Klog2, int total)
{
    int idx = blockIdx.x*256 + threadIdx.x;
    if (idx >= total) return;
    int K = 1 << Klog2;
    int n = idx >> Klog2, k = idx & (K-1);
    int N = total >> Klog2;
    dst[idx] = f2b(src[(size_t)k*N + n]);
}

// build wcatT [640][256] bf16 from w_off [256][400], w_attn [256][200]; bcat fp32[640]
__global__ __launch_bounds__(256) void prep_cat(const float* __restrict__ w_off,
                                                const float* __restrict__ w_attn,
                                                const float* __restrict__ b_off,
                                                const float* __restrict__ b_attn,
                                                bf16* __restrict__ wcatT,
                                                float* __restrict__ bcat)
{
    int idx = blockIdx.x*256 + threadIdx.x;
    if (idx >= NCAT*CC) return;
    int n = idx >> 8, k = idx & 255;
    float v = (n < 400) ? w_off[(size_t)k*400 + n]
            : (n < 600) ? w_attn[(size_t)k*200 + (n-400)] : 0.f;
    wcatT[idx] = f2b(v);
    if (idx < NCAT)
        bcat[idx] = (idx < 400) ? b_off[idx] : (idx < 600 ? b_attn[idx-400] : 0.f);
}

// ---------------- LayerNorm: one wave per token, 4 ch/lane ----------------------
__global__ __launch_bounds__(256) void ln_kernel(const float* __restrict__ x,
                                                 const float* __restrict__ g,
                                                 const float* __restrict__ b,
                                                 bf16* __restrict__ out)
{
    const int t = blockIdx.x*4 + (threadIdx.x >> 6);
    const int l = threadIdx.x & 63;
    const float4 v = *(const float4*)(x + (size_t)t*CC + l*4);
    float s  = v.x + v.y + v.z + v.w;
    float s2 = v.x*v.x + v.y*v.y + v.z*v.z + v.w*v.w;
    #pragma unroll
    for (int m = 1; m < 64; m <<= 1) { s += __shfl_xor(s, m); s2 += __shfl_xor(s2, m); }
    const float mean = s * (1.f/CC);
    const float var  = s2 * (1.f/CC) - mean*mean;
    const float rs   = 1.f / sqrtf(var + 1e-5f);
    const float4 gg = *(const float4*)(g + l*4);
    const float4 bb = *(const float4*)(b + l*4);
    bf16 o[4];
    o[0] = f2b((v.x-mean)*rs*gg.x + bb.x);
    o[1] = f2b((v.y-mean)*rs*gg.y + bb.y);
    o[2] = f2b((v.z-mean)*rs*gg.z + bb.z);
    o[3] = f2b((v.w-mean)*rs*gg.w + bb.w);
    *(uint2*)(out + (size_t)t*CC + l*4) = *(uint2*)o;
}

// ---------------- MFMA GEMM: A[M,K]bf16 @ Bt[N,K]bf16 + bias fp32 --------------
// tile 128x128, BK=64, 4 waves; XOR-swizzled LDS chunks for conflict-free b128.
// EPI: 0 = store bf16; 2 = gelu->bf16; 3 = +resid(fp32)->fp32
template<int EPI>
__global__ __launch_bounds__(256) void mfma_gemm(const bf16* __restrict__ A,
                                                 const bf16* __restrict__ Bt,
                                                 const float* __restrict__ bias,
                                                 void* __restrict__ outv,
                                                 const float* __restrict__ resid,
                                                 int K, int N)
{
    __shared__ short As[128*64];
    __shared__ short Bs[128*64];
    const int tid = threadIdx.x;
    const int w = tid >> 6, l = tid & 63;
    const int bm = blockIdx.x, bn = blockIdx.y;

    // staging assignment: 32 regions of 8 rows (16 A + 16 B); wave w takes 8.
    const bf16* sbase[8];
    short*      lbase[8];
    {
        const int lrow = l >> 3;            // 0..7 within region
        const int q    = (l & 7) ^ lrow;    // swizzled k-group
        #pragma unroll
        for (int j = 0; j < 8; j++) {
            int r = w*8 + j;
            bool isA = r < 16;
            int rr = isA ? r : r - 16;
            int row = rr*8 + lrow;          // tile-local row
            size_t grow = (size_t)((isA ? bm : bn)*128 + row);
            sbase[j] = (isA ? A : Bt) + grow*K + q*8;
            lbase[j] = (isA ? As : Bs) + rr*512;
        }
    }

    // fragment LDS offsets (in shorts), loop-invariant
    int aoff[2][4], boff[2][4];
    #pragma unroll
    for (int s = 0; s < 2; s++)
        #pragma unroll
        for (int i = 0; i < 4; i++) {
            int q = s*4 + (l >> 4);
            int m = 64*(w >> 1) + i*16 + (l & 15);
            int n = 64*(w &  1) + i*16 + (l & 15);
            aoff[s][i] = (m*8 + (q ^ (m & 7))) * 8;
            boff[s][i] = (n*8 + (q ^ (n & 7))) * 8;
        }

    f32x4 acc[4][4];
    #pragma unroll
    for (int i = 0; i < 4; i++)
        #pragma unroll
        for (int j = 0; j < 4; j++)
            acc[i][j] = (f32x4){0.f, 0.f, 0.f, 0.f};

    for (int k0 = 0; k0 < K; k0 += 64) {
        #pragma unroll
        for (int j = 0; j < 8; j++)
            gl2lds16(sbase[j] + k0, lbase[j]);
        __syncthreads();
        #pragma unroll
        for (int s = 0; s < 2; s++) {
            short8 af[4], bfr[4];
            #pragma unroll
            for (int i = 0; i < 4; i++) {
                af[i]  = *(const short8*)(As + aoff[s][i]);
                bfr[i] = *(const short8*)(Bs + boff[s][i]);
            }
            #pragma unroll
            for (int i = 0; i < 4; i++)
                #pragma unroll
                for (int j = 0; j < 4; j++)
                    acc[i][j] = __builtin_amdgcn_mfma_f32_16x16x32_bf16(af[i], bfr[j], acc[i][j], 0, 0, 0);
        }
        __syncthreads();
    }

    // epilogue: C/D layout col=lane&15, row=(lane>>4)*4+reg
    const int row0 = bm*128 + 64*(w >> 1) + (l >> 4)*4;
    const int col0 = bn*128 + 64*(w &  1) + (l & 15);
    #pragma unroll
    for (int i = 0; i < 4; i++) {
        #pragma unroll
        for (int j = 0; j < 4; j++) {
            const int col = col0 + j*16;
            const float bs = bias[col];
            #pragma unroll
            for (int r = 0; r < 4; r++) {
                const int row = row0 + i*16 + r;
                float v = acc[i][j][r] + bs;
                size_t o = (size_t)row * N + col;
                if (EPI == 0) {
                    ((bf16*)outv)[o] = f2b(v);
                } else if (EPI == 2) {
                    ((bf16*)outv)[o] = f2b(0.5f * v * (1.f + erff(v * 0.70710678118654752f)));
                } else {
                    ((float*)outv)[o] = v + resid[o];
                }
            }
        }
    }
}

// ---------------- Softmax over P=25 per (token, head), bf16 in/out --------------
__global__ __launch_bounds__(256) void softmax_kernel(bf16* __restrict__ cat)
{
    const int gid = blockIdx.x*256 + threadIdx.x;
    if (gid >= TT*NHEADS) return;
    bf16* p = cat + (size_t)(gid >> 3)*NCAT + 400 + (gid & 7)*PP;
    float e[PP];
    float m = b2f(p[0]);
    #pragma unroll
    for (int i = 1; i < PP; i++) m = fmaxf(m, b2f(p[i]));
    float s = 0.f;
    #pragma unroll
    for (int i = 0; i < PP; i++) { e[i] = expf(b2f(p[i]) - m); s += e[i]; }
    const float inv = 1.f / s;
    #pragma unroll
    for (int i = 0; i < PP; i++) p[i] = f2b(e[i] * inv);
}

// ---------------- Deformable sampling: wave64 = 1 token (8 heads x 8 lanes) -----
// each lane covers 4 channels, 8B gathers.
__global__ __launch_bounds__(256) void sample_kernel(const bf16* __restrict__ val,
                                                     const bf16* __restrict__ cat,
                                                     const float* __restrict__ refp,
                                                     bf16* __restrict__ samp)
{
    const int t     = blockIdx.x*4 + (threadIdx.x >> 6);
    const int l     = threadIdx.x & 63;
    const int hh    = l >> 3;
    const int lane8 = l & 7;
    const int c0    = hh*DHH + lane8*4;
    const int n     = (t >= LQ) ? 1 : 0;

    const float rx96 = refp[(size_t)t*2 + 0] * 96.f - 0.5f;
    const float ry96 = refp[(size_t)t*2 + 1] * 96.f - 0.5f;
    const bf16* row  = cat + (size_t)t*NCAT;
    const unsigned* offp = (const unsigned*)(row + hh*(PP*2));
    const bf16* awp  = row + 400 + hh*PP;
    const bf16* vbase = val + (size_t)n*LQ*CC + c0;

    float a0 = 0.f, a1 = 0.f, a2 = 0.f, a3 = 0.f;
    for (int p = 0; p < PP; p++) {
        const float a = b2f(awp[p]);
        const unsigned uo = offp[p];
        const float gx = rx96 + lo_bf(uo);
        const float gy = ry96 + hi_bf(uo);
        const float x0f = floorf(gx), y0f = floorf(gy);
        const float fx = gx - x0f, fy = gy - y0f;
        const int ix = (int)x0f, iy = (int)y0f;
        const float ax1 = a * fx, ax0 = a - ax1;
        #pragma unroll
        for (int d = 0; d < 4; d++) {
            const int dx = d & 1, dy = d >> 1;
            const int xi = ix + dx, yi = iy + dy;
            const float wt = (dx ? ax1 : ax0) * (dy ? fy : 1.f - fy);
            const bool valid = (xi >= 0) & (xi <= WW-1) & (yi >= 0) & (yi <= HH-1);
            const int xc = min(max(xi, 0), WW-1);
            const int yc = min(max(yi, 0), HH-1);
            const float wv = valid ? wt : 0.f;
            const uint2 vv = *(const uint2*)(vbase + (size_t)(yc*WW + xc)*CC);
            a0 += wv * lo_bf(vv.x);
            a1 += wv * hi_bf(vv.x);
            a2 += wv * lo_bf(vv.y);
            a3 += wv * hi_bf(vv.y);
        }
    }
    bf16 o[4] = { f2b(a0), f2b(a1), f2b(a2), f2b(a3) };
    *(uint2*)(samp + (size_t)t*CC + c0) = *(uint2*)o;
}

// ---------------- Launch ---------------------------------------------------------
extern "C" void kernel_launch(void* const* d_in, const int* in_sizes, int n_in,
                              void* d_out, int out_size, void* d_ws, size_t ws_size,
                              hipStream_t stream)
{
    const float* x      = (const float*)d_in[0];
    const float* refp   = (const float*)d_in[1];
    const float* ln1_g  = (const float*)d_in[4];
    const float* ln1_b  = (const float*)d_in[5];
    const float* w_off  = (const float*)d_in[6];
    const float* b_off  = (const float*)d_in[7];
    const float* w_attn = (const float*)d_in[8];
    const float* b_attn = (const float*)d_in[9];
    const float* w_val  = (const float*)d_in[10];
    const float* b_val  = (const float*)d_in[11];
    const float* w_out  = (const float*)d_in[12];
    const float* b_out  = (const float*)d_in[13];
    const float* ln2_g  = (const float*)d_in[14];
    const float* ln2_b  = (const float*)d_in[15];
    const float* w_fc1  = (const float*)d_in[16];
    const float* b_fc1  = (const float*)d_in[17];
    const float* w_fc2  = (const float*)d_in[18];
    const float* b_fc2  = (const float*)d_in[19];

    // workspace layout
    char* wsb = (char*)d_ws;
    bf16*  q     = (bf16*)(wsb + 0);           //  9,437,184
    bf16*  val   = (bf16*)(wsb + 9437184);     //  9,437,184
    bf16*  cat   = (bf16*)(wsb + 18874368);    // 23,592,960 (TT*640 bf16)
    bf16*  samp  = (bf16*)(wsb + 42467328);    //  9,437,184
    float* x1    = (float*)(wsb + 51904512);   // 18,874,368
    bf16*  wvalT = (bf16*)(wsb + 70778880);    //    131,072
    bf16*  woutT = (bf16*)(wsb + 70909952);    //    131,072
    bf16*  wfc1T = (bf16*)(wsb + 71041024);    //    524,288
    bf16*  wfc2T = (bf16*)(wsb + 71565312);    //    524,288
    bf16*  wcatT = (bf16*)(wsb + 72089600);    //    327,680
    float* bcat  = (float*)(wsb + 72417280);   //      2,560 -> 72,419,840 total
    bf16*  hid   = (bf16*)(wsb + 0);           // overlays q/val/cat (42.5MB >= 37.7MB)
    bf16*  y0    = samp;                       // overlays samp after out-proj

    if (ws_size < 72419840) return;

    const dim3 blk(256);
    // weight prep (bf16 transposed)
    prep_t<<<dim3((65536 +255)/256), blk, 0, stream>>>(w_val, wvalT, 8, 65536);
    prep_t<<<dim3((65536 +255)/256), blk, 0, stream>>>(w_out, woutT, 8, 65536);
    prep_t<<<dim3((262144+255)/256), blk, 0, stream>>>(w_fc1, wfc1T, 8, 262144);
    prep_t<<<dim3((262144+255)/256), blk, 0, stream>>>(w_fc2, wfc2T, 10, 262144);
    prep_cat<<<dim3((NCAT*CC+255)/256), blk, 0, stream>>>(w_off, w_attn, b_off, b_attn, wcatT, bcat);

    // 1. LN1
    ln_kernel<<<dim3(TT/4), blk, 0, stream>>>(x, ln1_g, ln1_b, q);
    // 2. value + (off|attn) GEMMs
    mfma_gemm<0><<<dim3(TT/128, CC/128),   blk, 0, stream>>>(q, wvalT, b_val, (void*)val, nullptr, CC, CC);
    mfma_gemm<0><<<dim3(TT/128, NCAT/128), blk, 0, stream>>>(q, wcatT, bcat,  (void*)cat, nullptr, CC, NCAT);
    // 3. softmax over P
    softmax_kernel<<<dim3(TT*NHEADS/256), blk, 0, stream>>>(cat);
    // 4. deformable sampling
    sample_kernel<<<dim3(TT/4), blk, 0, stream>>>(val, cat, refp, samp);
    // 5. out-projection + residual -> x1 (fp32)
    mfma_gemm<3><<<dim3(TT/128, CC/128),   blk, 0, stream>>>(samp, woutT, b_out, (void*)x1, x, CC, CC);
    // 6. LN2
    ln_kernel<<<dim3(TT/4), blk, 0, stream>>>(x1, ln2_g, ln2_b, y0);
    // 7. fc1 + gelu
    mfma_gemm<2><<<dim3(TT/128, HIDN/128), blk, 0, stream>>>(y0, wfc1T, b_fc1, (void*)hid, nullptr, CC, HIDN);
    // 8. fc2 + residual -> out (fp32)
    mfma_gemm<3><<<dim3(TT/128, CC/128),   blk, 0, stream>>>(hid, wfc2T, b_fc2, d_out, x1, HIDN, CC);
}

// Round 4
// 265.518 us; speedup vs baseline: 2.7789x; 1.1164x over previous
//
#include <hip/hip_runtime.h>
#include <hip/hip_bf16.h>
#include <math.h>

typedef __hip_bfloat16 bf16;
typedef __attribute__((ext_vector_type(8))) short short8;
typedef __attribute__((ext_vector_type(4))) float f32x4;

#define NB 2
#define HH 96
#define WW 96
#define CC 256
#define NHEADS 8
#define PP 25
#define DHH 32
#define HIDN 1024
#define LQ (HH*WW)          // 9216
#define TT (NB*LQ)          // 18432
#define NVC 896             // 256 val + 400 off + 200 attn + 40 pad
#define TB 8                // tokens per sample block

__device__ __forceinline__ float b2f(bf16 v){ return __bfloat162float(v); }
__device__ __forceinline__ bf16  f2b(float v){ return __float2bfloat16(v); }
__device__ __forceinline__ float lo_bf(unsigned u){ return __uint_as_float(u << 16); }
__device__ __forceinline__ float hi_bf(unsigned u){ return __uint_as_float(u & 0xffff0000u); }

__device__ __forceinline__ void gl2lds16(const void* g, void* l) {
    __builtin_amdgcn_global_load_lds(
        (const __attribute__((address_space(1))) unsigned int*)g,
        (__attribute__((address_space(3))) unsigned int*)l, 16, 0, 0);
}

// ---------------- all weight prep in one kernel ---------------------------------
// wvcT[896][256] = [w_val | w_off | w_attn | 0]^T ; wfc1T[1024][256]; wfc2T[256][1024];
// woutT[256][256]; bvc fp32[896]
__global__ __launch_bounds__(256) void prep_all(const float* __restrict__ w_val,
                                                const float* __restrict__ w_off,
                                                const float* __restrict__ w_attn,
                                                const float* __restrict__ w_fc1,
                                                const float* __restrict__ w_fc2,
                                                const float* __restrict__ w_out,
                                                const float* __restrict__ b_val,
                                                const float* __restrict__ b_off,
                                                const float* __restrict__ b_attn,
                                                bf16* __restrict__ wvcT,
                                                bf16* __restrict__ wfc1T,
                                                bf16* __restrict__ wfc2T,
                                                bf16* __restrict__ woutT,
                                                float* __restrict__ bvc)
{
    const int idx = blockIdx.x*256 + threadIdx.x;   // < 819200
    if (idx < 229376) {                              // wvcT
        int n = idx >> 8, k = idx & 255;
        float v = (n < 256) ? w_val[(size_t)k*256 + n]
                : (n < 656) ? w_off[(size_t)k*400 + (n-256)]
                : (n < 856) ? w_attn[(size_t)k*200 + (n-656)] : 0.f;
        wvcT[idx] = f2b(v);
    } else if (idx < 491520) {                       // wfc1T
        int j = idx - 229376; int n = j >> 8, k = j & 255;
        wfc1T[j] = f2b(w_fc1[(size_t)k*1024 + n]);
    } else if (idx < 753664) {                       // wfc2T
        int j = idx - 491520; int n = j >> 10, k = j & 1023;
        wfc2T[j] = f2b(w_fc2[(size_t)k*256 + n]);
    } else if (idx < 819200) {                       // woutT
        int j = idx - 753664; int n = j >> 8, k = j & 255;
        woutT[j] = f2b(w_out[(size_t)k*256 + n]);
    }
    if (idx < NVC)
        bvc[idx] = (idx < 256) ? b_val[idx]
                 : (idx < 656) ? b_off[idx-256]
                 : (idx < 856) ? b_attn[idx-656] : 0.f;
}

// ---------------- LayerNorm: one wave per token, 4 ch/lane ----------------------
__global__ __launch_bounds__(256) void ln_kernel(const float* __restrict__ x,
                                                 const float* __restrict__ g,
                                                 const float* __restrict__ b,
                                                 bf16* __restrict__ out)
{
    const int t = blockIdx.x*4 + (threadIdx.x >> 6);
    const int l = threadIdx.x & 63;
    const float4 v = *(const float4*)(x + (size_t)t*CC + l*4);
    float s  = v.x + v.y + v.z + v.w;
    float s2 = v.x*v.x + v.y*v.y + v.z*v.z + v.w*v.w;
    #pragma unroll
    for (int m = 1; m < 64; m <<= 1) { s += __shfl_xor(s, m); s2 += __shfl_xor(s2, m); }
    const float mean = s * (1.f/CC);
    const float var  = s2 * (1.f/CC) - mean*mean;
    const float rs   = 1.f / sqrtf(var + 1e-5f);
    const float4 gg = *(const float4*)(g + l*4);
    const float4 bb = *(const float4*)(b + l*4);
    bf16 o[4];
    o[0] = f2b((v.x-mean)*rs*gg.x + bb.x);
    o[1] = f2b((v.y-mean)*rs*gg.y + bb.y);
    o[2] = f2b((v.z-mean)*rs*gg.z + bb.z);
    o[3] = f2b((v.w-mean)*rs*gg.w + bb.w);
    *(uint2*)(out + (size_t)t*CC + l*4) = *(uint2*)o;
}

// ---------------- MFMA GEMM: A[M,K]bf16 @ Bt[N,K]bf16 + bias fp32 --------------
// tile 128x128, BK=64, 4 waves; XOR-swizzled LDS chunks for conflict-free b128.
// EPI: 0 = store bf16; 2 = gelu->bf16; 3 = +resid(fp32)->fp32
template<int EPI>
__global__ __launch_bounds__(256) void mfma_gemm(const bf16* __restrict__ A,
                                                 const bf16* __restrict__ Bt,
                                                 const float* __restrict__ bias,
                                                 void* __restrict__ outv,
                                                 const float* __restrict__ resid,
                                                 int K, int N)
{
    __shared__ short As[128*64];
    __shared__ short Bs[128*64];
    const int tid = threadIdx.x;
    const int w = tid >> 6, l = tid & 63;
    const int bm = blockIdx.x, bn = blockIdx.y;

    const bf16* sbase[8];
    short*      lbase[8];
    {
        const int lrow = l >> 3;
        const int q    = (l & 7) ^ lrow;
        #pragma unroll
        for (int j = 0; j < 8; j++) {
            int r = w*8 + j;
            bool isA = r < 16;
            int rr = isA ? r : r - 16;
            int row = rr*8 + lrow;
            size_t grow = (size_t)((isA ? bm : bn)*128 + row);
            sbase[j] = (isA ? A : Bt) + grow*K + q*8;
            lbase[j] = (isA ? As : Bs) + rr*512;
        }
    }

    int aoff[2][4], boff[2][4];
    #pragma unroll
    for (int s = 0; s < 2; s++)
        #pragma unroll
        for (int i = 0; i < 4; i++) {
            int q = s*4 + (l >> 4);
            int m = 64*(w >> 1) + i*16 + (l & 15);
            int n = 64*(w &  1) + i*16 + (l & 15);
            aoff[s][i] = (m*8 + (q ^ (m & 7))) * 8;
            boff[s][i] = (n*8 + (q ^ (n & 7))) * 8;
        }

    f32x4 acc[4][4];
    #pragma unroll
    for (int i = 0; i < 4; i++)
        #pragma unroll
        for (int j = 0; j < 4; j++)
            acc[i][j] = (f32x4){0.f, 0.f, 0.f, 0.f};

    for (int k0 = 0; k0 < K; k0 += 64) {
        #pragma unroll
        for (int j = 0; j < 8; j++)
            gl2lds16(sbase[j] + k0, lbase[j]);
        __syncthreads();
        #pragma unroll
        for (int s = 0; s < 2; s++) {
            short8 af[4], bfr[4];
            #pragma unroll
            for (int i = 0; i < 4; i++) {
                af[i]  = *(const short8*)(As + aoff[s][i]);
                bfr[i] = *(const short8*)(Bs + boff[s][i]);
            }
            #pragma unroll
            for (int i = 0; i < 4; i++)
                #pragma unroll
                for (int j = 0; j < 4; j++)
                    acc[i][j] = __builtin_amdgcn_mfma_f32_16x16x32_bf16(af[i], bfr[j], acc[i][j], 0, 0, 0);
        }
        __syncthreads();
    }

    const int row0 = bm*128 + 64*(w >> 1) + (l >> 4)*4;
    const int col0 = bn*128 + 64*(w &  1) + (l & 15);
    #pragma unroll
    for (int i = 0; i < 4; i++) {
        #pragma unroll
        for (int j = 0; j < 4; j++) {
            const int col = col0 + j*16;
            const float bs = bias[col];
            #pragma unroll
            for (int r = 0; r < 4; r++) {
                const int row = row0 + i*16 + r;
                float v = acc[i][j][r] + bs;
                size_t o = (size_t)row * N + col;
                if (EPI == 0) {
                    ((bf16*)outv)[o] = f2b(v);
                } else if (EPI == 2) {
                    ((bf16*)outv)[o] = f2b(0.5f * v * (1.f + erff(v * 0.70710678118654752f)));
                } else {
                    ((float*)outv)[o] = v + resid[o];
                }
            }
        }
    }
}

// ---------------- Softmax over P=25 per (token, head), in vc rows ---------------
__global__ __launch_bounds__(256) void softmax_kernel(bf16* __restrict__ vc)
{
    const int gid = blockIdx.x*256 + threadIdx.x;
    if (gid >= TT*NHEADS) return;
    bf16* p = vc + (size_t)(gid >> 3)*NVC + 656 + (gid & 7)*PP;
    float e[PP];
    float m = b2f(p[0]);
    #pragma unroll
    for (int i = 1; i < PP; i++) m = fmaxf(m, b2f(p[i]));
    float s = 0.f;
    #pragma unroll
    for (int i = 0; i < PP; i++) { e[i] = expf(b2f(p[i]) - m); s += e[i]; }
    const float inv = 1.f / s;
    #pragma unroll
    for (int i = 0; i < PP; i++) p[i] = f2b(e[i] * inv);
}

// ---------------- Deformable sampling, phase-split ------------------------------
// block = 8 tokens. Phase 1: 1600 (t,h,p) points -> tap weights + clamped idx in LDS.
// Phase 2: lane = (token, head, channel-oct), 16B gathers, 8 FMA per tap.
// XCD range swizzle: b&7 selects a contiguous 24-row token range per XCD.
__global__ __launch_bounds__(256) void sample_kernel(const bf16* __restrict__ vc,
                                                     const float* __restrict__ refp,
                                                     bf16* __restrict__ samp)
{
    __shared__ float4  w4[TB*200];
    __shared__ ushort4 i4[TB*200];
    const int b = blockIdx.x;                        // 2304 blocks
    const int tbase = ((b & 7)*288 + (b >> 3)) * TB;
    const int tid = threadIdx.x;

    // phase 1
    for (int i = tid; i < TB*200; i += 256) {
        const int tl  = (i*5243) >> 20;              // i/200
        const int rem = i - tl*200;
        const int h   = (rem*41) >> 10;              // rem/25
        const int p   = rem - h*25;
        const int t   = tbase + tl;
        const bf16* row = vc + (size_t)t*NVC;
        const unsigned uo = *(const unsigned*)(row + 256 + h*50 + 2*p);
        const float a  = b2f(row[656 + h*25 + p]);   // softmaxed weight
        const float gx = refp[(size_t)t*2+0]*96.f - 0.5f + lo_bf(uo);
        const float gy = refp[(size_t)t*2+1]*96.f - 0.5f + hi_bf(uo);
        const float x0f = floorf(gx), y0f = floorf(gy);
        const float fx = gx - x0f, fy = gy - y0f;
        const int ix = (int)x0f, iy = (int)y0f;
        float  wv[4];
        ushort ii[4];
        #pragma unroll
        for (int d = 0; d < 4; d++) {
            const int dx = d & 1, dy = d >> 1;
            const int xi = ix + dx, yi = iy + dy;
            const bool valid = (xi >= 0) & (xi <= WW-1) & (yi >= 0) & (yi <= HH-1);
            const int xc = min(max(xi, 0), WW-1);
            const int yc = min(max(yi, 0), HH-1);
            ii[d] = (ushort)(yc*WW + xc);
            wv[d] = valid ? a * (dx ? fx : 1.f-fx) * (dy ? fy : 1.f-fy) : 0.f;
        }
        w4[i] = (float4){wv[0], wv[1], wv[2], wv[3]};
        i4[i] = (ushort4){ii[0], ii[1], ii[2], ii[3]};
    }
    __syncthreads();

    // phase 2
    const int wv_ = tid >> 6, l = tid & 63;
    const int tl  = wv_*2 + (l >> 5);
    const int r   = l & 31;
    const int h   = r >> 2, oct = r & 3;
    const int c0  = h*DHH + oct*8;
    const int t   = tbase + tl;
    const int n   = (t >= LQ) ? 1 : 0;
    const bf16* pv = vc + (size_t)n*LQ*NVC + c0;
    const int pib = tl*200 + h*25;

    float acc[8] = {0.f,0.f,0.f,0.f,0.f,0.f,0.f,0.f};
    for (int p = 0; p < PP; p++) {
        const float4  w  = w4[pib + p];
        const ushort4 id = i4[pib + p];
        const float  wt_[4] = {w.x, w.y, w.z, w.w};
        const ushort id_[4] = {id.x, id.y, id.z, id.w};
        #pragma unroll
        for (int d = 0; d < 4; d++) {
            const float wt = wt_[d];
            const uint4 vv = *(const uint4*)(pv + (size_t)id_[d]*NVC);
            acc[0] += wt*lo_bf(vv.x); acc[1] += wt*hi_bf(vv.x);
            acc[2] += wt*lo_bf(vv.y); acc[3] += wt*hi_bf(vv.y);
            acc[4] += wt*lo_bf(vv.z); acc[5] += wt*hi_bf(vv.z);
            acc[6] += wt*lo_bf(vv.w); acc[7] += wt*hi_bf(vv.w);
        }
    }
    bf16 o[8];
    #pragma unroll
    for (int j = 0; j < 8; j++) o[j] = f2b(acc[j]);
    *(uint4*)(samp + (size_t)t*CC + c0) = *(uint4*)o;
}

// ---------------- Launch ---------------------------------------------------------
extern "C" void kernel_launch(void* const* d_in, const int* in_sizes, int n_in,
                              void* d_out, int out_size, void* d_ws, size_t ws_size,
                              hipStream_t stream)
{
    const float* x      = (const float*)d_in[0];
    const float* refp   = (const float*)d_in[1];
    const float* ln1_g  = (const float*)d_in[4];
    const float* ln1_b  = (const float*)d_in[5];
    const float* w_off  = (const float*)d_in[6];
    const float* b_off  = (const float*)d_in[7];
    const float* w_attn = (const float*)d_in[8];
    const float* b_attn = (const float*)d_in[9];
    const float* w_val  = (const float*)d_in[10];
    const float* b_val  = (const float*)d_in[11];
    const float* w_out  = (const float*)d_in[12];
    const float* b_out  = (const float*)d_in[13];
    const float* ln2_g  = (const float*)d_in[14];
    const float* ln2_b  = (const float*)d_in[15];
    const float* w_fc1  = (const float*)d_in[16];
    const float* b_fc1  = (const float*)d_in[17];
    const float* w_fc2  = (const float*)d_in[18];
    const float* b_fc2  = (const float*)d_in[19];

    // workspace layout
    char* wsb = (char*)d_ws;
    bf16*  q     = (bf16*)(wsb + 0);           //  9,437,184
    bf16*  vc    = (bf16*)(wsb + 9437184);     // 33,030,144 (TT*896 bf16)
    bf16*  samp  = (bf16*)(wsb + 42467328);    //  9,437,184
    float* x1    = (float*)(wsb + 51904512);   // 18,874,368
    bf16*  wvcT  = (bf16*)(wsb + 70778880);    //    458,752
    bf16*  wfc1T = (bf16*)(wsb + 71237632);    //    524,288
    bf16*  wfc2T = (bf16*)(wsb + 71761920);    //    524,288
    bf16*  woutT = (bf16*)(wsb + 72286208);    //    131,072
    float* bvc   = (float*)(wsb + 72417280);   //      3,584 -> 72,420,864 total
    bf16*  hid   = (bf16*)(wsb + 0);           // overlays q+vc (42.5MB >= 37.7MB)
    bf16*  y0    = samp;                       // overlays samp after out-proj

    if (ws_size < 72420864) return;

    const dim3 blk(256);
    // 0. weight prep (single kernel)
    prep_all<<<dim3(3200), blk, 0, stream>>>(w_val, w_off, w_attn, w_fc1, w_fc2, w_out,
                                             b_val, b_off, b_attn,
                                             wvcT, wfc1T, wfc2T, woutT, bvc);
    // 1. LN1
    ln_kernel<<<dim3(TT/4), blk, 0, stream>>>(x, ln1_g, ln1_b, q);
    // 2. fused value|off|attn GEMM -> vc
    mfma_gemm<0><<<dim3(TT/128, NVC/128), blk, 0, stream>>>(q, wvcT, bvc, (void*)vc, nullptr, CC, NVC);
    // 3. softmax over P (in vc rows)
    softmax_kernel<<<dim3(TT*NHEADS/256), blk, 0, stream>>>(vc);
    // 4. deformable sampling
    sample_kernel<<<dim3(TT/TB), blk, 0, stream>>>(vc, refp, samp);
    // 5. out-projection + residual -> x1 (fp32)
    mfma_gemm<3><<<dim3(TT/128, CC/128),   blk, 0, stream>>>(samp, woutT, b_out, (void*)x1, x, CC, CC);
    // 6. LN2
    ln_kernel<<<dim3(TT/4), blk, 0, stream>>>(x1, ln2_g, ln2_b, y0);
    // 7. fc1 + gelu
    mfma_gemm<2><<<dim3(TT/128, HIDN/128), blk, 0, stream>>>(y0, wfc1T, b_fc1, (void*)hid, nullptr, CC, HIDN);
    // 8. fc2 + residual -> out (fp32)
    mfma_gemm<3><<<dim3(TT/128, CC/128),   blk, 0, stream>>>(hid, wfc2T, b_fc2, d_out, x1, HIDN, CC);
}

// Round 5
// 249.540 us; speedup vs baseline: 2.9569x; 1.0640x over previous
//
#include <hip/hip_runtime.h>
#include <hip/hip_bf16.h>
#include <math.h>

typedef __hip_bfloat16 bf16;
typedef __attribute__((ext_vector_type(8))) short short8;
typedef __attribute__((ext_vector_type(4))) float f32x4;

#define NB 2
#define HH 96
#define WW 96
#define CC 256
#define NHEADS 8
#define PP 25
#define DHH 32
#define HIDN 1024
#define LQ (HH*WW)          // 9216
#define TT (NB*LQ)          // 18432
#define NVC 896             // 256 val + 400 off + 200 attn + 40 pad
#define TB 8                // tokens per sample block

__device__ __forceinline__ float b2f(bf16 v){ return __bfloat162float(v); }
__device__ __forceinline__ bf16  f2b(float v){ return __float2bfloat16(v); }
__device__ __forceinline__ float lo_bf(unsigned u){ return __uint_as_float(u << 16); }
__device__ __forceinline__ float hi_bf(unsigned u){ return __uint_as_float(u & 0xffff0000u); }

__device__ __forceinline__ void gl2lds16(const void* g, void* l) {
    __builtin_amdgcn_global_load_lds(
        (const __attribute__((address_space(1))) unsigned int*)g,
        (__attribute__((address_space(3))) unsigned int*)l, 16, 0, 0);
}

// ---------------- all weight prep in one kernel ---------------------------------
__global__ __launch_bounds__(256) void prep_all(const float* __restrict__ w_val,
                                                const float* __restrict__ w_off,
                                                const float* __restrict__ w_attn,
                                                const float* __restrict__ w_fc1,
                                                const float* __restrict__ w_fc2,
                                                const float* __restrict__ w_out,
                                                const float* __restrict__ b_val,
                                                const float* __restrict__ b_off,
                                                const float* __restrict__ b_attn,
                                                bf16* __restrict__ wvcT,
                                                bf16* __restrict__ wfc1T,
                                                bf16* __restrict__ wfc2T,
                                                bf16* __restrict__ woutT,
                                                float* __restrict__ bvc)
{
    const int idx = blockIdx.x*256 + threadIdx.x;   // < 819200
    if (idx < 229376) {                              // wvcT [896][256]
        int n = idx >> 8, k = idx & 255;
        float v = (n < 256) ? w_val[(size_t)k*256 + n]
                : (n < 656) ? w_off[(size_t)k*400 + (n-256)]
                : (n < 856) ? w_attn[(size_t)k*200 + (n-656)] : 0.f;
        wvcT[idx] = f2b(v);
    } else if (idx < 491520) {                       // wfc1T [1024][256]
        int j = idx - 229376; int n = j >> 8, k = j & 255;
        wfc1T[j] = f2b(w_fc1[(size_t)k*1024 + n]);
    } else if (idx < 753664) {                       // wfc2T [256][1024]
        int j = idx - 491520; int n = j >> 10, k = j & 1023;
        wfc2T[j] = f2b(w_fc2[(size_t)k*256 + n]);
    } else if (idx < 819200) {                       // woutT [256][256]
        int j = idx - 753664; int n = j >> 8, k = j & 255;
        woutT[j] = f2b(w_out[(size_t)k*256 + n]);
    }
    if (idx < NVC)
        bvc[idx] = (idx < 256) ? b_val[idx]
                 : (idx < 656) ? b_off[idx-256]
                 : (idx < 856) ? b_attn[idx-656] : 0.f;
}

// ---------------- LayerNorm: one wave per token, 4 ch/lane ----------------------
__global__ __launch_bounds__(256) void ln_kernel(const float* __restrict__ x,
                                                 const float* __restrict__ g,
                                                 const float* __restrict__ b,
                                                 bf16* __restrict__ out)
{
    const int t = blockIdx.x*4 + (threadIdx.x >> 6);
    const int l = threadIdx.x & 63;
    const float4 v = *(const float4*)(x + (size_t)t*CC + l*4);
    float s  = v.x + v.y + v.z + v.w;
    float s2 = v.x*v.x + v.y*v.y + v.z*v.z + v.w*v.w;
    #pragma unroll
    for (int m = 1; m < 64; m <<= 1) { s += __shfl_xor(s, m); s2 += __shfl_xor(s2, m); }
    const float mean = s * (1.f/CC);
    const float var  = s2 * (1.f/CC) - mean*mean;
    const float rs   = 1.f / sqrtf(var + 1e-5f);
    const float4 gg = *(const float4*)(g + l*4);
    const float4 bb = *(const float4*)(b + l*4);
    bf16 o[4];
    o[0] = f2b((v.x-mean)*rs*gg.x + bb.x);
    o[1] = f2b((v.y-mean)*rs*gg.y + bb.y);
    o[2] = f2b((v.z-mean)*rs*gg.z + bb.z);
    o[3] = f2b((v.w-mean)*rs*gg.w + bb.w);
    *(uint2*)(out + (size_t)t*CC + l*4) = *(uint2*)o;
}

// ---------------- MFMA GEMM: A[M,K]bf16 @ Bt[N,K]bf16 + bias fp32 --------------
// tile 128x128, BK=64, 4 waves; XOR-swizzled LDS chunks. Compile-time K,N.
// EPI: 0 = store bf16; 2 = gelu->bf16; 3 = +resid(fp32)->fp32
template<int EPI, int K, int N>
__global__ __launch_bounds__(256) void mfma_gemm(const bf16* __restrict__ A,
                                                 const bf16* __restrict__ Bt,
                                                 const float* __restrict__ bias,
                                                 void* __restrict__ outv,
                                                 const float* __restrict__ resid)
{
    __shared__ short As[128*64];
    __shared__ short Bs[128*64];
    const int tid = threadIdx.x;
    const int w = tid >> 6, l = tid & 63;
    const int bm = blockIdx.x, bn = blockIdx.y;

    const bf16* sbase[8];
    short*      lbase[8];
    {
        const int lrow = l >> 3;
        const int q    = (l & 7) ^ lrow;
        #pragma unroll
        for (int j = 0; j < 8; j++) {
            int r = w*8 + j;
            bool isA = r < 16;
            int rr = isA ? r : r - 16;
            int row = rr*8 + lrow;
            size_t grow = (size_t)((isA ? bm : bn)*128 + row);
            sbase[j] = (isA ? A : Bt) + grow*K + q*8;
            lbase[j] = (isA ? As : Bs) + rr*512;
        }
    }

    int aoff[2][4], boff[2][4];
    #pragma unroll
    for (int s = 0; s < 2; s++)
        #pragma unroll
        for (int i = 0; i < 4; i++) {
            int q = s*4 + (l >> 4);
            int m = 64*(w >> 1) + i*16 + (l & 15);
            int n = 64*(w &  1) + i*16 + (l & 15);
            aoff[s][i] = (m*8 + (q ^ (m & 7))) * 8;
            boff[s][i] = (n*8 + (q ^ (n & 7))) * 8;
        }

    f32x4 acc[4][4];
    #pragma unroll
    for (int i = 0; i < 4; i++)
        #pragma unroll
        for (int j = 0; j < 4; j++)
            acc[i][j] = (f32x4){0.f, 0.f, 0.f, 0.f};

    for (int k0 = 0; k0 < K; k0 += 64) {
        #pragma unroll
        for (int j = 0; j < 8; j++)
            gl2lds16(sbase[j] + k0, lbase[j]);
        __syncthreads();
        #pragma unroll
        for (int s = 0; s < 2; s++) {
            short8 af[4], bfr[4];
            #pragma unroll
            for (int i = 0; i < 4; i++) {
                af[i]  = *(const short8*)(As + aoff[s][i]);
                bfr[i] = *(const short8*)(Bs + boff[s][i]);
            }
            #pragma unroll
            for (int i = 0; i < 4; i++)
                #pragma unroll
                for (int j = 0; j < 4; j++)
                    acc[i][j] = __builtin_amdgcn_mfma_f32_16x16x32_bf16(af[i], bfr[j], acc[i][j], 0, 0, 0);
        }
        __syncthreads();
    }

    const int row0 = bm*128 + 64*(w >> 1) + (l >> 4)*4;
    const int col0 = bn*128 + 64*(w &  1) + (l & 15);
    #pragma unroll
    for (int i = 0; i < 4; i++) {
        #pragma unroll
        for (int j = 0; j < 4; j++) {
            const int col = col0 + j*16;
            const float bs = bias[col];
            #pragma unroll
            for (int r = 0; r < 4; r++) {
                const int row = row0 + i*16 + r;
                float v = acc[i][j][r] + bs;
                size_t o = (size_t)row * N + col;
                if (EPI == 0) {
                    ((bf16*)outv)[o] = f2b(v);
                } else if (EPI == 2) {
                    ((bf16*)outv)[o] = f2b(0.5f * v * (1.f + erff(v * 0.70710678118654752f)));
                } else {
                    ((float*)outv)[o] = v + resid[o];
                }
            }
        }
    }
}

// ---------------- Deformable sampling, phase-split, fused softmax ---------------
// block = 8 tokens. Phase 1: 64 (t,h) pairs x 4 threads: softmax over 25 logits
// (quad shuffle-reduce) + tap weights/indices -> 16B Tap records in LDS (25.6KB).
// Phase 2: lane = (token, head, channel-oct), ds_read_b128 + 16B gathers.
struct __align__(16) Tap { _Float16 w[4]; unsigned short i[4]; };

__global__ __launch_bounds__(256) void sample_kernel(const bf16* __restrict__ vc,
                                                     const float* __restrict__ refp,
                                                     bf16* __restrict__ samp)
{
    __shared__ Tap taps[TB*200];
    const int b = blockIdx.x;                        // 2304 blocks
    const int tbase = ((b & 7)*288 + (b >> 3)) * TB; // XCD range swizzle
    const int tid = threadIdx.x;

    // ---- phase 1: fused softmax + tap computation
    {
        const int pair = tid >> 2;                   // 0..63 = (tl, h)
        const int j    = tid & 3;                    // point sub-lane
        const int tl   = pair >> 3;
        const int h    = pair & 7;
        const int t    = tbase + tl;
        const bf16* row = vc + (size_t)t*NVC;

        // my logits: p = j + 4k
        float lg[7];
        #pragma unroll
        for (int k = 0; k < 7; k++) {
            int p = j + 4*k;
            lg[k] = (p < PP) ? b2f(row[656 + h*25 + p]) : -1e30f;
        }
        float m = lg[0];
        #pragma unroll
        for (int k = 1; k < 7; k++) m = fmaxf(m, lg[k]);
        m = fmaxf(m, __shfl_xor(m, 1));
        m = fmaxf(m, __shfl_xor(m, 2));
        float s = 0.f;
        float ex[7];
        #pragma unroll
        for (int k = 0; k < 7; k++) {
            ex[k] = (j + 4*k < PP) ? expf(lg[k] - m) : 0.f;
            s += ex[k];
        }
        s += __shfl_xor(s, 1);
        s += __shfl_xor(s, 2);
        const float inv = 1.f / s;

        const float rx96 = refp[(size_t)t*2 + 0]*96.f - 0.5f;
        const float ry96 = refp[(size_t)t*2 + 1]*96.f - 0.5f;
        const unsigned* offp = (const unsigned*)(row + 256 + h*50);

        #pragma unroll
        for (int k = 0; k < 7; k++) {
            const int p = j + 4*k;
            if (p >= PP) break;
            const float a = ex[k] * inv;
            const unsigned uo = offp[p];
            const float gx = rx96 + lo_bf(uo);
            const float gy = ry96 + hi_bf(uo);
            const float x0f = floorf(gx), y0f = floorf(gy);
            const float fx = gx - x0f, fy = gy - y0f;
            const int ix = (int)x0f, iy = (int)y0f;
            Tap tp;
            #pragma unroll
            for (int d = 0; d < 4; d++) {
                const int dx = d & 1, dy = d >> 1;
                const int xi = ix + dx, yi = iy + dy;
                const bool valid = (xi >= 0) & (xi <= WW-1) & (yi >= 0) & (yi <= HH-1);
                const int xc = min(max(xi, 0), WW-1);
                const int yc = min(max(yi, 0), HH-1);
                tp.i[d] = (unsigned short)(yc*WW + xc);
                tp.w[d] = (_Float16)(valid ? a * (dx ? fx : 1.f-fx) * (dy ? fy : 1.f-fy) : 0.f);
            }
            taps[tl*200 + h*25 + p] = tp;
        }
    }
    __syncthreads();

    // ---- phase 2: gather + accumulate
    const int wv_ = tid >> 6, l = tid & 63;
    const int tl  = wv_*2 + (l >> 5);
    const int r   = l & 31;
    const int h   = r >> 2, oct = r & 3;
    const int c0  = h*DHH + oct*8;
    const int t   = tbase + tl;
    const int n   = (t >= LQ) ? 1 : 0;
    const bf16* pv = vc + (size_t)n*LQ*NVC + c0;
    const int pib = tl*200 + h*25;

    float acc[8] = {0.f,0.f,0.f,0.f,0.f,0.f,0.f,0.f};
    for (int p = 0; p < PP; p++) {
        const uint4 tv = *((const uint4*)taps + (pib + p));
        const _Float16* wp_ = (const _Float16*)&tv;
        const unsigned short* ip_ = (const unsigned short*)&tv + 4;
        #pragma unroll
        for (int d = 0; d < 4; d++) {
            const float wt = (float)wp_[d];
            const uint4 vv = *(const uint4*)(pv + (size_t)ip_[d]*NVC);
            acc[0] += wt*lo_bf(vv.x); acc[1] += wt*hi_bf(vv.x);
            acc[2] += wt*lo_bf(vv.y); acc[3] += wt*hi_bf(vv.y);
            acc[4] += wt*lo_bf(vv.z); acc[5] += wt*hi_bf(vv.z);
            acc[6] += wt*lo_bf(vv.w); acc[7] += wt*hi_bf(vv.w);
        }
    }
    bf16 o[8];
    #pragma unroll
    for (int j2 = 0; j2 < 8; j2++) o[j2] = f2b(acc[j2]);
    *(uint4*)(samp + (size_t)t*CC + c0) = *(uint4*)o;
}

// ---------------- Launch ---------------------------------------------------------
extern "C" void kernel_launch(void* const* d_in, const int* in_sizes, int n_in,
                              void* d_out, int out_size, void* d_ws, size_t ws_size,
                              hipStream_t stream)
{
    const float* x      = (const float*)d_in[0];
    const float* refp   = (const float*)d_in[1];
    const float* ln1_g  = (const float*)d_in[4];
    const float* ln1_b  = (const float*)d_in[5];
    const float* w_off  = (const float*)d_in[6];
    const float* b_off  = (const float*)d_in[7];
    const float* w_attn = (const float*)d_in[8];
    const float* b_attn = (const float*)d_in[9];
    const float* w_val  = (const float*)d_in[10];
    const float* b_val  = (const float*)d_in[11];
    const float* w_out  = (const float*)d_in[12];
    const float* b_out  = (const float*)d_in[13];
    const float* ln2_g  = (const float*)d_in[14];
    const float* ln2_b  = (const float*)d_in[15];
    const float* w_fc1  = (const float*)d_in[16];
    const float* b_fc1  = (const float*)d_in[17];
    const float* w_fc2  = (const float*)d_in[18];
    const float* b_fc2  = (const float*)d_in[19];

    // workspace layout
    char* wsb = (char*)d_ws;
    bf16*  q     = (bf16*)(wsb + 0);           //  9,437,184
    bf16*  vc    = (bf16*)(wsb + 9437184);     // 33,030,144 (TT*896 bf16)
    bf16*  samp  = (bf16*)(wsb + 42467328);    //  9,437,184
    float* x1    = (float*)(wsb + 51904512);   // 18,874,368
    bf16*  wvcT  = (bf16*)(wsb + 70778880);    //    458,752
    bf16*  wfc1T = (bf16*)(wsb + 71237632);    //    524,288
    bf16*  wfc2T = (bf16*)(wsb + 71761920);    //    524,288
    bf16*  woutT = (bf16*)(wsb + 72286208);    //    131,072
    float* bvc   = (float*)(wsb + 72417280);   //      3,584 -> 72,420,864 total
    bf16*  hid   = (bf16*)(wsb + 0);           // overlays q+vc (42.5MB >= 37.7MB)
    bf16*  y0    = samp;                       // overlays samp after out-proj

    if (ws_size < 72420864) return;

    const dim3 blk(256);
    // 0. weight prep
    prep_all<<<dim3(3200), blk, 0, stream>>>(w_val, w_off, w_attn, w_fc1, w_fc2, w_out,
                                             b_val, b_off, b_attn,
                                             wvcT, wfc1T, wfc2T, woutT, bvc);
    // 1. LN1
    ln_kernel<<<dim3(TT/4), blk, 0, stream>>>(x, ln1_g, ln1_b, q);
    // 2. fused value|off|attn GEMM -> vc
    mfma_gemm<0,256,NVC><<<dim3(TT/128, NVC/128), blk, 0, stream>>>(q, wvcT, bvc, (void*)vc, nullptr);
    // 3. deformable sampling (softmax fused in)
    sample_kernel<<<dim3(TT/TB), blk, 0, stream>>>(vc, refp, samp);
    // 4. out-projection + residual -> x1 (fp32)
    mfma_gemm<3,256,CC><<<dim3(TT/128, CC/128), blk, 0, stream>>>(samp, woutT, b_out, (void*)x1, x);
    // 5. LN2
    ln_kernel<<<dim3(TT/4), blk, 0, stream>>>(x1, ln2_g, ln2_b, y0);
    // 6. fc1 + gelu
    mfma_gemm<2,256,HIDN><<<dim3(TT/128, HIDN/128), blk, 0, stream>>>(y0, wfc1T, b_fc1, (void*)hid, nullptr);
    // 7. fc2 + residual -> out (fp32)
    mfma_gemm<3,HIDN,CC><<<dim3(TT/128, CC/128), blk, 0, stream>>>(hid, wfc2T, b_fc2, d_out, x1);
}